// Round 15
// baseline (234.523 us; speedup 1.0000x reference)
//
#include <hip/hip_runtime.h>

#define NP_   16384
#define NQ_   8192
#define NB_   2
#define K_    16
#define QPB   8            // queries per block (2 groups of 4, each group = 2 waves)
#define TPB   256
#define HALF  (NP_/2)      // 8192 points per wave
#define GPH   (HALF/64)    // 128 group-iterations

#define IDX_OFF 0
#define RS_OFF  (NB_*NQ_*K_)        // 262144
#define RS_N    (NB_*NQ_+1)         // 16385
#define DST_OFF (RS_OFF + RS_N)     // 278529

typedef unsigned long long ull;

__global__ __launch_bounds__(TPB, 4) void knn_kernel(const float* __restrict__ pts,
                                                     const float* __restrict__ qrs,
                                                     float* __restrict__ out)
{
    // Validated exact-match formula (R6):
    //   sq, sp : forward sum, separate mul/add rounds
    //   ip     : forward FMA chain  fma(z,qz, fma(y,qy, round(x*qx)))
    //   d      : fmaf(-2, ip, sq+sp)
    // Scanned d is transported by shuffle, never recomputed -> exact.
    #pragma clang fp contract(off)

    __shared__ float2 mg[2][64];   // 1KB: half-1 lists for the block's 2 groups

    const int tid  = threadIdx.x;
    const int lane = tid & 63;
    const int s    = lane & 15;               // rank this lane owns
    const int wv   = tid >> 6;                // wave 0..3
    const int qgrp = wv >> 1;                 // 0..1: which 4-query group
    const int half = wv & 1;                  // 0: points [0,8192)  1: [8192,16384)

    const int q0   = blockIdx.x * QPB + (qgrp << 2);
    const int gq   = q0 + (lane >> 4);        // lane's own query
    const int batch = gq >> 13;
    const int gofs  = batch * NP_;
    const float* pb = pts + (size_t)gofs * 3;

    // the wave's 4 queries (register-resident)
    float qxv[4], qyv[4], qzv[4], sqv[4];
    #pragma unroll
    for (int qi = 0; qi < 4; ++qi) {
        qxv[qi] = qrs[(q0+qi)*3+0];
        qyv[qi] = qrs[(q0+qi)*3+1];
        qzv[qi] = qrs[(q0+qi)*3+2];
        sqv[qi] = qxv[qi]*qxv[qi] + qyv[qi]*qyv[qi] + qzv[qi]*qzv[qi]; // fwd, no FMA
    }

    const float INF = __int_as_float(0x7f800000);
    float hd = INF; int hi = 0x7fffffff;      // distributed top-16: rank-s of own query
    float th0 = INF, th1 = INF, th2 = INF, th3 = INF;
    const ull gmask = 0xFFFFull << (lane & 48);

    // insert events of ballot-mask bq into group q's distributed list;
    // every 16 pops, re-filter the mask against the current 16th-best
    // (strict < : exact stable semantics; kills the t=0 seed blow-up).
    auto process = [&](ull bq, float dq, int q, int base) {
        int done = 0;
        while (bq) {
            int L = (int)__ffsll(bq) - 1;
            bq &= bq - 1;
            float dstar = __shfl(dq, L);      // value-exact transport
            int   istar = base + L;
            if ((lane >> 4) == q) {           // group q's 16 lanes insert
                ull bb = __ballot(hd <= dstar);   // ties: existing (lower idx) first
                int pos = __popcll(bb & gmask);
                float sd = __shfl_up(hd, 1, 16);
                int   si = __shfl_up(hi, 1, 16);
                if (pos < K_) {               // pos==16: stale event, drop
                    if (s == pos)      { hd = dstar; hi = istar; }
                    else if (s > pos)  { hd = sd;    hi = si;    }
                }
            }
            if (++done == K_) {
                float thq = __shfl(hd, (q << 4) + 15, 64);
                bq &= __ballot(dq < thq);
                done = 0;
            }
        }
    };

    const int pbase0 = half * HALF;           // this wave's point range (local idx)
    for (int g = 0; g < GPH; ++g) {
        int pid = pbase0 + (g << 6) + lane;   // 64 distinct points, coalesced
        const float* pp = pb + (size_t)pid * 3;
        float x = pp[0], y = pp[1], z = pp[2];
        float sp = x*x + y*y + z*z;           // fwd, no FMA
        float ip0 = fmaf(z, qzv[0], fmaf(y, qyv[0], __fmul_rn(x, qxv[0])));
        float ip1 = fmaf(z, qzv[1], fmaf(y, qyv[1], __fmul_rn(x, qxv[1])));
        float ip2 = fmaf(z, qzv[2], fmaf(y, qyv[2], __fmul_rn(x, qxv[2])));
        float ip3 = fmaf(z, qzv[3], fmaf(y, qyv[3], __fmul_rn(x, qxv[3])));
        float d0 = fmaf(-2.0f, ip0, sqv[0] + sp);
        float d1 = fmaf(-2.0f, ip1, sqv[1] + sp);
        float d2 = fmaf(-2.0f, ip2, sqv[2] + sp);
        float d3 = fmaf(-2.0f, ip3, sqv[3] + sp);
        ull b0 = __ballot(d0 < th0);          // strict <: exact selection rule
        ull b1 = __ballot(d1 < th1);
        ull b2 = __ballot(d2 < th2);
        ull b3 = __ballot(d3 < th3);
        if (b0 | b1 | b2 | b3) {              // uniform scalar skip
            int base = pbase0 + (g << 6);
            process(b0, d0, 0, base);
            process(b1, d1, 1, base);
            process(b2, d2, 2, base);
            process(b3, d3, 3, base);
            th0 = __shfl(hd, 15, 64);         // per-query true 16th-best (this half)
            th1 = __shfl(hd, 31, 64);
            th2 = __shfl(hd, 47, 64);
            th3 = __shfl(hd, 63, 64);
        }
    }

    // ---- merge the two halves (half-0 indices always < half-1: stable) ----
    if (half == 1) mg[qgrp][lane] = make_float2(hd, __int_as_float(hi));
    __syncthreads();
    if (half == 0) {
        // Batcher halver: min(A[s], B[15-s]) = smallest-16 set (bitonic seq)
        float2 o = mg[qgrp][(lane & 48) | (15 - s)];
        float bd = o.x; int bi = __float_as_int(o.y);
        bool takeB = (bd < hd) || (bd == hd && bi < hi);
        float md = takeB ? bd : hd;
        int   mi = takeB ? bi : hi;
        // bitonic cleanup: 4 stages, ascending by (d, idx)
        #pragma unroll
        for (int off = 8; off >= 1; off >>= 1) {
            float od = __shfl_xor(md, off, 16);
            int   oi = __shfl_xor(mi, off, 16);
            bool pl = (od < md) || (od == md && oi < mi);  // partner lex-smaller
            bool keepmin = (s & off) == 0;
            bool take = (keepmin == pl);
            md = take ? od : md;  mi = take ? oi : mi;
        }
        out[IDX_OFF + gq*K_ + s] = (float)(mi + gofs);
        out[DST_OFF + gq*K_ + s] = fmaxf(md, 0.0f);
    }

    // row_splits = arange(16385) * 16, written as float (exact)
    int gt = blockIdx.x * TPB + tid;
    if (gt < RS_N) out[RS_OFF + gt] = (float)(gt * K_);
}

extern "C" void kernel_launch(void* const* d_in, const int* in_sizes, int n_in,
                              void* d_out, int out_size, void* d_ws, size_t ws_size,
                              hipStream_t stream)
{
    const float* pts = (const float*)d_in[0];
    const float* qrs = (const float*)d_in[1];
    float* out = (float*)d_out;
    (void)in_sizes; (void)n_in; (void)out_size; (void)d_ws; (void)ws_size;

    dim3 grid(NB_ * NQ_ / QPB);   // 2048 blocks = 8 blocks/CU
    dim3 block(TPB);              // 256 threads (4 waves)
    knn_kernel<<<grid, block, 0, stream>>>(pts, qrs, out);
}

// Round 16
// 168.809 us; speedup vs baseline: 1.3893x; 1.3893x over previous
//
#include <hip/hip_runtime.h>

#define NP_   16384
#define NQ_   8192
#define NB_   2
#define K_    16
#define QPB   16           // queries per block (4 per wave x 4 waves)
#define TPB   256
#define TILE  1024         // points per LDS tile (16KB)
#define NTILES (NP_/TILE)  // 16
#define GPT   (TILE/64)    // 16 group-iterations per tile

#define IDX_OFF 0
#define RS_OFF  (NB_*NQ_*K_)        // 262144
#define RS_N    (NB_*NQ_+1)         // 16385
#define DST_OFF (RS_OFF + RS_N)     // 278529

typedef unsigned long long ull;

__global__ __launch_bounds__(TPB, 4) void knn_kernel(const float* __restrict__ pts,
                                                     const float* __restrict__ qrs,
                                                     float* __restrict__ out)
{
    // Validated exact-match formula (R6):
    //   sq, sp : forward sum, separate mul/add rounds
    //   ip     : forward FMA chain  fma(z,qz, fma(y,qy, round(x*qx)))
    //   d      : fmaf(-2, ip, sq+sp)
    // Scanned d is transported by shuffle, never recomputed -> exact.
    #pragma clang fp contract(off)

    __shared__ float4 tile[TILE];   // 16KB

    const int tid  = threadIdx.x;
    const int lane = tid & 63;
    const int s    = lane & 15;               // rank this lane owns
    const int g    = lane >> 4;               // query-group within wave (0..3)
    const int gq   = blockIdx.x * QPB + (tid >> 4);   // lane's own query
    const int batch = gq >> 13;
    const int gofs  = batch * NP_;
    const float* pb = pts + (size_t)gofs * 3;

    // the wave's 4 queries (register-resident)
    const int qbase = blockIdx.x * QPB + ((tid >> 6) << 2);
    float qxv[4], qyv[4], qzv[4], sqv[4];
    #pragma unroll
    for (int qi = 0; qi < 4; ++qi) {
        qxv[qi] = qrs[(qbase+qi)*3+0];
        qyv[qi] = qrs[(qbase+qi)*3+1];
        qzv[qi] = qrs[(qbase+qi)*3+2];
        sqv[qi] = qxv[qi]*qxv[qi] + qyv[qi]*qyv[qi] + qzv[qi]*qzv[qi];  // fwd, no FMA
    }

    const float INF = __int_as_float(0x7f800000);
    float hd = INF; int hi = 0x7fffffff;      // distributed top-16: rank-s of own query
    float th0 = INF, th1 = INF, th2 = INF, th3 = INF;
    const ull gmask = 0xFFFFull << (lane & 48);

    for (int t = 0; t < NTILES; ++t) {
        __syncthreads();
        #pragma unroll
        for (int k = 0; k < TILE/TPB; ++k) {
            int lp = tid + k*TPB;
            int gp = t*TILE + lp;
            float x = pb[gp*3+0], y = pb[gp*3+1], z = pb[gp*3+2];
            float sp = x*x + y*y + z*z;       // fwd, no FMA
            tile[lp] = make_float4(x, y, z, sp);
        }
        __syncthreads();

        #pragma unroll 2
        for (int gi = 0; gi < GPT; ++gi) {
            float4 p = tile[gi*64 + lane];    // 64 distinct points, full LDS width
            float ip0 = fmaf(p.z, qzv[0], fmaf(p.y, qyv[0], __fmul_rn(p.x, qxv[0])));
            float ip1 = fmaf(p.z, qzv[1], fmaf(p.y, qyv[1], __fmul_rn(p.x, qxv[1])));
            float ip2 = fmaf(p.z, qzv[2], fmaf(p.y, qyv[2], __fmul_rn(p.x, qxv[2])));
            float ip3 = fmaf(p.z, qzv[3], fmaf(p.y, qyv[3], __fmul_rn(p.x, qxv[3])));
            float d0 = fmaf(-2.0f, ip0, sqv[0] + p.w);
            float d1 = fmaf(-2.0f, ip1, sqv[1] + p.w);
            float d2 = fmaf(-2.0f, ip2, sqv[2] + p.w);
            float d3 = fmaf(-2.0f, ip3, sqv[3] + p.w);
            ull m0 = __ballot(d0 < th0);      // strict <: exact selection rule
            ull m1 = __ballot(d1 < th1);
            ull m2 = __ballot(d2 < th2);
            ull m3 = __ballot(d3 < th3);
            if (m0 | m1 | m2 | m3) {          // uniform scalar skip
                const int base = t*TILE + gi*64;
                int done = 0;
                while (m0 | m1 | m2 | m3) {
                    // one pending event per group, all processed in parallel
                    int L0 = (int)__ffsll(m0) - 1;  m0 &= m0 - 1;
                    int L1 = (int)__ffsll(m1) - 1;  m1 &= m1 - 1;
                    int L2 = (int)__ffsll(m2) - 1;  m2 &= m2 - 1;
                    int L3 = (int)__ffsll(m3) - 1;  m3 &= m3 - 1;
                    float r0 = __shfl(d0, L0 & 63);
                    float r1 = __shfl(d1, L1 & 63);
                    float r2 = __shfl(d2, L2 & 63);
                    float r3 = __shfl(d3, L3 & 63);
                    float dstar = (g==0) ? r0 : (g==1) ? r1 : (g==2) ? r2 : r3;
                    int   Lg    = (g==0) ? L0 : (g==1) ? L1 : (g==2) ? L2 : L3;
                    if (Lg < 0) dstar = INF;  // empty group: pos==16 -> no-op
                    int istar = base + Lg;
                    // full-wave distributed insert (4 groups at once)
                    ull bb = __ballot(hd <= dstar);   // ties: existing first
                    int pos = (int)__popcll(bb & gmask);
                    float sd = __shfl_up(hd, 1, 16);
                    int   si = __shfl_up(hi, 1, 16);
                    if (pos < K_) {                   // pos==16: stale/sentinel
                        if (s == pos)      { hd = dstar; hi = istar; }
                        else if (s > pos)  { hd = sd;    hi = si;    }
                    }
                    if (++done == K_) {               // periodic stale-kill
                        th0 = __shfl(hd, 15, 64);
                        th1 = __shfl(hd, 31, 64);
                        th2 = __shfl(hd, 47, 64);
                        th3 = __shfl(hd, 63, 64);
                        m0 &= __ballot(d0 < th0);
                        m1 &= __ballot(d1 < th1);
                        m2 &= __ballot(d2 < th2);
                        m3 &= __ballot(d3 < th3);
                        done = 0;
                    }
                }
                th0 = __shfl(hd, 15, 64);     // per-query true 16th-best
                th1 = __shfl(hd, 31, 64);
                th2 = __shfl(hd, 47, 64);
                th3 = __shfl(hd, 63, 64);
            }
        }
    }

    // output: lane s already holds rank-s of its query (no merge needed)
    out[IDX_OFF + gq*K_ + s] = (float)(hi + gofs);
    out[DST_OFF + gq*K_ + s] = fmaxf(hd, 0.0f);

    // row_splits = arange(16385) * 16, written as float (exact)
    int gt = blockIdx.x * TPB + tid;
    if (gt < RS_N) out[RS_OFF + gt] = (float)(gt * K_);
}

extern "C" void kernel_launch(void* const* d_in, const int* in_sizes, int n_in,
                              void* d_out, int out_size, void* d_ws, size_t ws_size,
                              hipStream_t stream)
{
    const float* pts = (const float*)d_in[0];
    const float* qrs = (const float*)d_in[1];
    float* out = (float*)d_out;
    (void)in_sizes; (void)n_in; (void)out_size; (void)d_ws; (void)ws_size;

    dim3 grid(NB_ * NQ_ / QPB);   // 1024 blocks
    dim3 block(TPB);              // 256 threads
    knn_kernel<<<grid, block, 0, stream>>>(pts, qrs, out);
}